// Round 8
// baseline (281.369 us; speedup 1.0000x reference)
//
#include <hip/hip_runtime.h>

#define INF_F 1e20f
#define B_ 16
#define Q_ 64
#define M_ 512
#define F_ 16
#define D_ 512

typedef __attribute__((ext_vector_type(8))) short short8v;
typedef __attribute__((ext_vector_type(4))) float f32x4;

static __device__ __forceinline__ float bits_f(unsigned u) { return __uint_as_float(u); }

// float4 -> hi bf16x4 (uint2) + residual-lo bf16x4 (uint2), truncation split
static __device__ __forceinline__ void split4(float4 v, uint2& H, uint2& L) {
    unsigned hx = __float_as_uint(v.x) & 0xffff0000u, hy = __float_as_uint(v.y) & 0xffff0000u;
    unsigned hz = __float_as_uint(v.z) & 0xffff0000u, hw = __float_as_uint(v.w) & 0xffff0000u;
    H.x = (hx >> 16) | hy;
    H.y = (hz >> 16) | hw;
    L.x = (__float_as_uint(v.x - bits_f(hx)) >> 16) | (__float_as_uint(v.y - bits_f(hy)) & 0xffff0000u);
    L.y = (__float_as_uint(v.z - bits_f(hz)) >> 16) | (__float_as_uint(v.w - bits_f(hw)) & 0xffff0000u);
}

static __device__ __forceinline__ short8v mk8(uint2 a, uint2 b) {
    union { uint4 u; short8v s; } r;
    r.u = make_uint4(a.x, a.y, b.x, b.y);
    return r.s;
}

// K0: q fragment-image: unit u = [b][kc][lg][row] -> 8 bf16 (hi & lo)
// containing query[b][row][kc*32 + lg*8 .. +7]
__global__ __launch_bounds__(256) void k_q_split(
    const float* __restrict__ q, short8v* __restrict__ qh, short8v* __restrict__ ql)
{
    int u = blockIdx.x * 256 + threadIdx.x;          // 0..65535
    int row = u & 63, lg = (u >> 6) & 3, kc = (u >> 8) & 15, b = u >> 12;
    const float4* q4 = (const float4*)q;
    size_t s = (size_t)(b * 64 + row) * 128 + kc * 8 + lg * 2;
    float4 v0 = q4[s], v1 = q4[s + 1];
    uint2 H0, L0, H1, L1;
    split4(v0, H0, L0);
    split4(v1, H1, L1);
    *(uint4*)&qh[u] = make_uint4(H0.x, H0.y, H1.x, H1.y);
    *(uint4*)&ql[u] = make_uint4(L0.x, L0.y, L1.x, L1.y);
}

// K1: 3 roles by bid: r = (bid>>4)%3, mg = bid>>4)/3, b = bid&15 (XCD pin: bid%8=b%8)
//  r==0:  streamer: weighted f-sum of in_memory -> in_mem_base (t<128)
//                   + plain f-sum of out_memory -> out_mem_sum (t>=128); 8 m.
//  r==1/2: MFMA GEMM over 8 m x 32 q (qhalf=r-1). Q-frags live in LDS (lgkmcnt
//          domain); B-frags in a 4-deep register ring (vmcnt domain) -> counted
//          waits never drain the HBM prefetch. masks + f-max -> att_qm.
__global__ __launch_bounds__(256, 2) void k_att_mfma(
    const short8v* __restrict__ qhg, const short8v* __restrict__ qlg,
    const float* __restrict__ in_mem, const float* __restrict__ out_mem,
    const float* __restrict__ ctx_mask, const float* __restrict__ query_mask,
    float* __restrict__ att_qm, float* __restrict__ in_mem_base,
    float* __restrict__ out_mem_sum)
{
    __shared__ short8v QF[2][2048];      // 64 KB: [hi/lo][kc*128 + lg*32 + row]

    const int bid = blockIdx.x;
    const int b   = bid & 15;
    const int t16 = bid >> 4;
    const int r   = t16 % 3;
    const int mg  = t16 / 3;
    const int m0  = mg * 8;
    const int t   = threadIdx.x;

    if (r == 0) {
        // ---------------- streamer path ----------------
        const int th = t & 127;
        const bool is_in = (t < 128);
        const int msel = th >> 4, col4 = (th >> 1) & 7, half = th & 1;

        float wj[8];
        if (is_in) {
            const float* cm = ctx_mask + ((size_t)b * M_ + m0 + msel) * F_;
            float wv[16]; float mx = -INF_F;
            #pragma unroll
            for (int f = 0; f < 16; ++f) {
                float c = cm[f];
                float v = c - (1.0f - c) * INF_F;
                wv[f] = v; mx = fmaxf(mx, v);
            }
            float sum = 0.f;
            #pragma unroll
            for (int f = 0; f < 16; ++f) { wv[f] = __expf(wv[f] - mx); sum += wv[f]; }
            float inv = 1.0f / sum;
            #pragma unroll
            for (int j = 0; j < 8; ++j) wj[j] = wv[half * 8 + j] * inv;
        } else {
            #pragma unroll
            for (int j = 0; j < 8; ++j) wj[j] = 1.0f;
        }

        const float4* fsrc = is_in ? (const float4*)in_mem : (const float4*)out_mem;
        float4* fdst       = is_in ? (float4*)in_mem_base : (float4*)out_mem_sum;
        const size_t fbase = (size_t)((b * M_ + m0 + msel) * F_ + half * 8) * 128 + col4;
        const size_t fob   = (size_t)(b * M_ + m0 + msel) * 128 + col4;

        float4 fa[8], fb[8];
        #pragma unroll
        for (int j = 0; j < 8; ++j) fa[j] = fsrc[fbase + (size_t)j * 128];

#define FBODY(kc_, cur, nxt) do {                                              \
        if ((kc_) < 15) {                                                      \
            _Pragma("unroll")                                                  \
            for (int j = 0; j < 8; ++j)                                        \
                nxt[j] = fsrc[fbase + (size_t)j * 128 + ((kc_) + 1) * 8];      \
        }                                                                      \
        float4 s = make_float4(0, 0, 0, 0);                                    \
        _Pragma("unroll")                                                      \
        for (int j = 0; j < 8; ++j) {                                          \
            s.x += wj[j] * cur[j].x; s.y += wj[j] * cur[j].y;                  \
            s.z += wj[j] * cur[j].z; s.w += wj[j] * cur[j].w;                  \
        }                                                                      \
        s.x += __shfl_xor(s.x, 1, 64); s.y += __shfl_xor(s.y, 1, 64);          \
        s.z += __shfl_xor(s.z, 1, 64); s.w += __shfl_xor(s.w, 1, 64);          \
        if (half == 0) fdst[fob + (kc_) * 8] = s;                              \
    } while (0)

        #pragma unroll
        for (int it = 0; it < 8; ++it) {
            FBODY(2 * it, fa, fb);
            FBODY(2 * it + 1, fb, fa);
        }
#undef FBODY
        return;
    }

    // ---------------- MFMA path ----------------
    const int qhalf = r - 1;
    const int w = t >> 6, lane = t & 63;
    const int lr = lane & 15, lg = lane >> 4;
    const float4* in4 = (const float4*)in_mem;
    // lane's B-fragment row bases (float4 units); +kc*8 per chunk
    const size_t rb0 = (size_t)((b * M_ + m0 + 2 * w) * F_ + lr) * 128 + lg * 2;
    const size_t rb1 = rb0 + (size_t)F_ * 128;

    // issue the 4-deep B ring FIRST (overlaps the Q fill below)
    float4 sb[4][4];
    #pragma unroll
    for (int s = 0; s < 4; ++s) {
        size_t o = (size_t)s * 8;
        sb[s][0] = in4[rb0 + o];     sb[s][1] = in4[rb0 + o + 1];
        sb[s][2] = in4[rb1 + o];     sb[s][3] = in4[rb1 + o + 1];
    }

    // fill Q LDS (this block's 32-q half, fragment order)
    #pragma unroll
    for (int j = 0; j < 8; ++j) {
        int i = t + j * 256;                         // 0..2047
        int kc = i >> 7, lg2 = (i >> 5) & 3, row = i & 31;
        int src = b * 4096 + kc * 256 + lg2 * 64 + qhalf * 32 + row;
        QF[0][i] = qhg[src];
        QF[1][i] = qlg[src];
    }
    __syncthreads();

    f32x4 acc[2][2];
    #pragma unroll
    for (int i = 0; i < 2; ++i)
        #pragma unroll
        for (int j = 0; j < 2; ++j) acc[i][j] = (f32x4){0, 0, 0, 0};

    // q fragments: [0]=hi tq0, [1]=lo tq0, [2]=hi tq1, [3]=lo tq1
    short8v qA[4], qB[4];
    qA[0] = QF[0][lg * 32 + lr];        qA[1] = QF[1][lg * 32 + lr];
    qA[2] = QF[0][lg * 32 + 16 + lr];   qA[3] = QF[1][lg * 32 + 16 + lr];

#define MBODY(kc_, QC, QN) do {                                                \
        if ((kc_) + 1 < 16) {   /* ds-prefetch next chunk's q-frags */         \
            int u = ((kc_) + 1) * 128 + lg * 32 + lr;                          \
            QN[0] = QF[0][u];        QN[1] = QF[1][u];                         \
            QN[2] = QF[0][u + 16];   QN[3] = QF[1][u + 16];                    \
        }                                                                      \
        {                                                                      \
            const int sl = (kc_) & 3;                                          \
            uint2 H0, L0, H1, L1;                                              \
            split4(sb[sl][0], H0, L0); split4(sb[sl][1], H1, L1);              \
            short8v bh0 = mk8(H0, H1), bl0 = mk8(L0, L1);                      \
            split4(sb[sl][2], H0, L0); split4(sb[sl][3], H1, L1);              \
            short8v bh1 = mk8(H0, H1), bl1 = mk8(L0, L1);                      \
            if ((kc_) + 4 < 16) {   /* refill ring slot, stays in flight */    \
                size_t o = (size_t)((kc_) + 4) * 8;                            \
                sb[sl][0] = in4[rb0 + o];  sb[sl][1] = in4[rb0 + o + 1];       \
                sb[sl][2] = in4[rb1 + o];  sb[sl][3] = in4[rb1 + o + 1];       \
            }                                                                  \
            __builtin_amdgcn_s_setprio(1);                                     \
            _Pragma("unroll")                                                  \
            for (int tq = 0; tq < 2; ++tq) {                                   \
                short8v ah = QC[2 * tq], al = QC[2 * tq + 1];                  \
                acc[0][tq] = __builtin_amdgcn_mfma_f32_16x16x32_bf16(ah, bh0, acc[0][tq], 0, 0, 0); \
                acc[0][tq] = __builtin_amdgcn_mfma_f32_16x16x32_bf16(ah, bl0, acc[0][tq], 0, 0, 0); \
                acc[0][tq] = __builtin_amdgcn_mfma_f32_16x16x32_bf16(al, bh0, acc[0][tq], 0, 0, 0); \
                acc[1][tq] = __builtin_amdgcn_mfma_f32_16x16x32_bf16(ah, bh1, acc[1][tq], 0, 0, 0); \
                acc[1][tq] = __builtin_amdgcn_mfma_f32_16x16x32_bf16(ah, bl1, acc[1][tq], 0, 0, 0); \
                acc[1][tq] = __builtin_amdgcn_mfma_f32_16x16x32_bf16(al, bh1, acc[1][tq], 0, 0, 0); \
            }                                                                  \
            __builtin_amdgcn_s_setprio(0);                                     \
        }                                                                      \
    } while (0)

    #pragma unroll
    for (int it = 0; it < 8; ++it) {
        MBODY(2 * it,     qA, qB);
        MBODY(2 * it + 1, qB, qA);
    }
#undef MBODY

    // masks + max over f (16-lane groups) -> att_qm; wave w owns m-tiles 2w,2w+1
    #pragma unroll
    for (int tm = 0; tm < 2; ++tm) {
        int m = m0 + 2 * w + tm;
        float cmv = ctx_mask[((size_t)b * M_ + m) * F_ + lr];
        #pragma unroll
        for (int tq = 0; tq < 2; ++tq) {
            #pragma unroll
            for (int rg = 0; rg < 4; ++rg) {
                int q = qhalf * 32 + tq * 16 + lg * 4 + rg;
                float qmv = query_mask[b * Q_ + q];
                float v = acc[tm][tq][rg];
                v = cmv * v - (1.0f - cmv) * INF_F;
                v = qmv * v - (1.0f - qmv) * INF_F;
                #pragma unroll
                for (int sh = 1; sh < 16; sh <<= 1) v = fmaxf(v, __shfl_xor(v, sh, 64));
                if (lr == 0)
                    att_qm[((size_t)b * Q_ + q) * M_ + m] = v;
            }
        }
    }
}

// K2: softmax over M (in-block) + new_query = query + probs @ out_mem_sum; 4 q/block
__global__ __launch_bounds__(128) void k_new_query(
    const float* __restrict__ att, const float* __restrict__ query,
    const float* __restrict__ out_sum, float* __restrict__ new_q)
{
    __shared__ float P[4][512];
    int bid = blockIdx.x;
    int b = bid & 15, qc = bid >> 4;       // qc 0..15
    int t = threadIdx.x;
    {
        int qi = t >> 5, l32 = t & 31;
        const float* row = att + ((size_t)b * Q_ + qc * 4 + qi) * M_;
        float vals[16]; float mx = -INF_F;
        #pragma unroll
        for (int i = 0; i < 16; ++i) { vals[i] = row[l32 + i * 32]; mx = fmaxf(mx, vals[i]); }
        #pragma unroll
        for (int s = 1; s < 32; s <<= 1) mx = fmaxf(mx, __shfl_xor(mx, s, 32));
        float sm = 0.f;
        #pragma unroll
        for (int i = 0; i < 16; ++i) { vals[i] = __expf(vals[i] - mx); sm += vals[i]; }
        #pragma unroll
        for (int s = 1; s < 32; s <<= 1) sm += __shfl_xor(sm, s, 32);
        float inv = 1.0f / sm;
        #pragma unroll
        for (int i = 0; i < 16; ++i) P[qi][l32 + i * 32] = vals[i] * inv;
    }
    __syncthreads();
    int c = t;
    const float4* o4 = (const float4*)out_sum + (size_t)b * M_ * 128 + c;
    const float4* q4 = (const float4*)query + ((size_t)b * Q_ + qc * 4) * 128 + c;
    float4 acc[4];
    #pragma unroll
    for (int qi = 0; qi < 4; ++qi) acc[qi] = q4[(size_t)qi * 128];
    for (int mm = 0; mm < M_; mm += 4) {
        float4 o0 = o4[(size_t)(mm + 0) * 128];
        float4 o1 = o4[(size_t)(mm + 1) * 128];
        float4 o2 = o4[(size_t)(mm + 2) * 128];
        float4 o3 = o4[(size_t)(mm + 3) * 128];
        #pragma unroll
        for (int qi = 0; qi < 4; ++qi) {
            float4 p = *(const float4*)&P[qi][mm];
            acc[qi].x += p.x * o0.x + p.y * o1.x + p.z * o2.x + p.w * o3.x;
            acc[qi].y += p.x * o0.y + p.y * o1.y + p.z * o2.y + p.w * o3.y;
            acc[qi].z += p.x * o0.z + p.y * o1.z + p.z * o2.z + p.w * o3.z;
            acc[qi].w += p.x * o0.w + p.y * o1.w + p.z * o2.w + p.w * o3.w;
        }
    }
    float4* n4 = (float4*)new_q + ((size_t)b * Q_ + qc * 4) * 128 + c;
    #pragma unroll
    for (int qi = 0; qi < 4; ++qi) n4[(size_t)qi * 128] = acc[qi];
}

// K3: softmax over Q (in-block) + in_mem += p2 @ new_query; 4 m/block
__global__ __launch_bounds__(128) void k_in_mem(
    const float* __restrict__ att, const float* __restrict__ new_q,
    float* __restrict__ in_mem_io)
{
    __shared__ float P[4][64];
    int bid = blockIdx.x;
    int b = bid & 15, mc = bid >> 4;       // mc 0..127
    int m0 = mc * 4;
    int t = threadIdx.x;
    {
        int mi = t >> 5, l32 = t & 31;
        float v[2]; float mx = -INF_F;
        #pragma unroll
        for (int i = 0; i < 2; ++i) {
            v[i] = att[((size_t)b * Q_ + l32 + i * 32) * M_ + m0 + mi];
            mx = fmaxf(mx, v[i]);
        }
        #pragma unroll
        for (int s = 1; s < 32; s <<= 1) mx = fmaxf(mx, __shfl_xor(mx, s, 32));
        float sm = 0.f;
        #pragma unroll
        for (int i = 0; i < 2; ++i) { v[i] = __expf(v[i] - mx); sm += v[i]; }
        #pragma unroll
        for (int s = 1; s < 32; s <<= 1) sm += __shfl_xor(sm, s, 32);
        float inv = 1.0f / sm;
        #pragma unroll
        for (int i = 0; i < 2; ++i) P[mi][l32 + i * 32] = v[i] * inv;
    }
    __syncthreads();
    int c = t;
    float4* io = (float4*)in_mem_io + ((size_t)b * M_ + m0) * 128 + c;
    const float4* n4 = (const float4*)new_q + (size_t)b * Q_ * 128 + c;
    float4 acc[4];
    #pragma unroll
    for (int mi = 0; mi < 4; ++mi) acc[mi] = io[(size_t)mi * 128];
    for (int q = 0; q < Q_; q += 4) {
        float4 n0 = n4[(size_t)(q + 0) * 128];
        float4 n1 = n4[(size_t)(q + 1) * 128];
        float4 n2 = n4[(size_t)(q + 2) * 128];
        float4 n3 = n4[(size_t)(q + 3) * 128];
        #pragma unroll
        for (int mi = 0; mi < 4; ++mi) {
            float4 p = *(const float4*)&P[mi][q];
            acc[mi].x += p.x * n0.x + p.y * n1.x + p.z * n2.x + p.w * n3.x;
            acc[mi].y += p.x * n0.y + p.y * n1.y + p.z * n2.y + p.w * n3.y;
            acc[mi].z += p.x * n0.z + p.y * n1.z + p.z * n2.z + p.w * n3.z;
            acc[mi].w += p.x * n0.w + p.y * n1.w + p.z * n2.w + p.w * n3.w;
        }
    }
    #pragma unroll
    for (int mi = 0; mi < 4; ++mi) io[(size_t)mi * 128] = acc[mi];
}

extern "C" void kernel_launch(void* const* d_in, const int* in_sizes, int n_in,
                              void* d_out, int out_size, void* d_ws, size_t ws_size,
                              hipStream_t stream)
{
    const float* query      = (const float*)d_in[0];
    const float* in_mem     = (const float*)d_in[1];
    const float* out_mem    = (const float*)d_in[2];
    const float* ctx_mask   = (const float*)d_in[3];
    const float* query_mask = (const float*)d_in[4];

    float* out = (float*)d_out;
    float* new_q      = out;                             // B*Q*D
    float* in_mem_out = out + (size_t)B_*Q_*D_;          // B*M*D
    float* out_mem_o  = in_mem_out + (size_t)B_*M_*D_;   // B*M*D

    float* ws       = (float*)d_ws;
    float* att_qm   = ws;                                // B*Q*M floats (2 MB)
    short8v* qh     = (short8v*)(ws + (size_t)B_*Q_*M_); // 65536 units (1 MB)
    short8v* ql     = qh + 65536;                        // 1 MB

    hipLaunchKernelGGL(k_q_split, dim3(256), dim3(256), 0, stream, query, qh, ql);
    hipLaunchKernelGGL(k_att_mfma, dim3(64 * 3 * B_), dim3(256), 0, stream,
                       qh, ql, in_mem, out_mem, ctx_mask, query_mask,
                       att_qm, in_mem_out, out_mem_o);
    hipLaunchKernelGGL(k_new_query, dim3(16 * B_), dim3(128), 0, stream,
                       att_qm, query, out_mem_o, new_q);
    hipLaunchKernelGGL(k_in_mem, dim3(128 * B_), dim3(128), 0, stream,
                       att_qm, new_q, in_mem_out);
}

// Round 9
// 243.478 us; speedup vs baseline: 1.1556x; 1.1556x over previous
//
#include <hip/hip_runtime.h>

#define INF_F 1e20f
#define B_ 16
#define Q_ 64
#define M_ 512
#define F_ 16
#define D_ 512

typedef __attribute__((ext_vector_type(8))) short short8v;
typedef __attribute__((ext_vector_type(4))) float f32x4;

static __device__ __forceinline__ float bits_f(unsigned u) { return __uint_as_float(u); }

// float4 -> hi bf16x4 (uint2) + residual-lo bf16x4 (uint2), truncation split
static __device__ __forceinline__ void split4(float4 v, uint2& H, uint2& L) {
    unsigned hx = __float_as_uint(v.x) & 0xffff0000u, hy = __float_as_uint(v.y) & 0xffff0000u;
    unsigned hz = __float_as_uint(v.z) & 0xffff0000u, hw = __float_as_uint(v.w) & 0xffff0000u;
    H.x = (hx >> 16) | hy;
    H.y = (hz >> 16) | hw;
    L.x = (__float_as_uint(v.x - bits_f(hx)) >> 16) | (__float_as_uint(v.y - bits_f(hy)) & 0xffff0000u);
    L.y = (__float_as_uint(v.z - bits_f(hz)) >> 16) | (__float_as_uint(v.w - bits_f(hw)) & 0xffff0000u);
}

// K0: q fragment-image: unit u = [b][kc][lg][row] -> 8 bf16 (hi & lo)
// containing query[b][row][kc*32 + lg*8 .. +7]
__global__ __launch_bounds__(256) void k_q_split(
    const float* __restrict__ q, short8v* __restrict__ qh, short8v* __restrict__ ql)
{
    int u = blockIdx.x * 256 + threadIdx.x;          // 0..65535
    int row = u & 63, lg = (u >> 6) & 3, kc = (u >> 8) & 15, b = u >> 12;
    const float4* q4 = (const float4*)q;
    size_t s = (size_t)(b * 64 + row) * 128 + kc * 8 + lg * 2;
    float4 v0 = q4[s], v1 = q4[s + 1];
    uint2 H0, L0, H1, L1;
    split4(v0, H0, L0);
    split4(v1, H1, L1);
    *(uint4*)&qh[u] = make_uint4(H0.x, H0.y, H1.x, H1.y);
    *(uint4*)&ql[u] = make_uint4(L0.x, L0.y, L1.x, L1.y);
}

// K1: single-read fused kernel. Per block: 8 m x 64 q of one batch.
// Wave w owns m-tiles {2w, 2w+1}: stages their 32 in_mem rows to a WAVE-PRIVATE
// LDS region (no barriers anywhere; DS ops are wave-ordered), MFMAs them against
// q-fragments (L2-hot image, 1 chunk ahead), computes the ctx-softmax-weighted
// f-sum from the SAME staging registers (in_mem read once total), and f-sums
// out_memory from its only read. All load issues FIFO-monotone -> counted vmcnt.
__global__ __launch_bounds__(256) void k_att_fused(
    const short8v* __restrict__ qhg, const short8v* __restrict__ qlg,
    const float* __restrict__ in_mem, const float* __restrict__ out_mem,
    const float* __restrict__ ctx_mask, const float* __restrict__ query_mask,
    float* __restrict__ att_qm, float* __restrict__ in_mem_base,
    float* __restrict__ out_mem_sum)
{
    // 128 rows x 32 bf16, pitch 40 shorts (80B); granule swz ^((row&1)<<1)
    __shared__ __align__(16) short Mh[5120];   // 10 KB
    __shared__ __align__(16) short Ml[5120];   // 10 KB

    const int bid = blockIdx.x;
    const int b   = bid & 15;            // XCD pin (b%8): q-image L2 locality
    const int m0  = (bid >> 4) * 8;      // 8 m per block
    const int t   = threadIdx.x;
    const int w   = t >> 6;              // wave 0..3 -> m-tiles {2w, 2w+1}
    const int lane = t & 63;
    const int lr  = lane & 15;           // fragment row (= f)
    const int lg  = lane >> 4;           // k-granule / f-quad
    const int c   = lane & 7;            // float4 column
    const int b0  = (lane >> 3) & 1;     // staged-m parity
    const int mm  = 2 * w + b0;          // my staged m (0..7)

    // softmax-over-f weights for my staged m, my 4 f's (f = lg*4 + i)
    float wj[4];
    {
        const float* cm = ctx_mask + ((size_t)b * M_ + m0 + mm) * F_;
        float wv[16]; float mx = -INF_F;
        #pragma unroll
        for (int f = 0; f < 16; ++f) {
            float cv = cm[f];
            float v = cv - (1.0f - cv) * INF_F;
            wv[f] = v; mx = fmaxf(mx, v);
        }
        float s = 0.f;
        #pragma unroll
        for (int f = 0; f < 16; ++f) { wv[f] = __expf(wv[f] - mx); s += wv[f]; }
        float inv = 1.0f / s;
        #pragma unroll
        for (int i = 0; i < 4; ++i) wj[i] = wv[lg * 4 + i] * inv;
    }

    const float4* in4 = (const float4*)in_mem;
    const float4* ot4 = (const float4*)out_mem;
    // staged rows: (m0+mm)*16 + lg*4 + i  ->  global float4 idx grow + i*128 (+kc*8)
    const int grow  = ((b * M_ + m0 + mm) * F_ + lg * 4) * 128 + c;
    const int qb0   = b * 4096 + lg * 64 + lr;          // q-image unit (+kc*256 +tq*16)
    const int obase = (b * M_ + m0 + mm) * 128 + c;     // f-sum output (+kc*8)

    f32x4 acc[2][4];
    #pragma unroll
    for (int i = 0; i < 2; ++i)
        #pragma unroll
        for (int j = 0; j < 4; ++j) acc[i][j] = (f32x4){0, 0, 0, 0};

    float4 si[2][4], so[2][4];
    short8v qf[2][8];

    // prologue: chunk-0 loads (FIFO: stg+out first, then qf)
    #pragma unroll
    for (int i = 0; i < 4; ++i) { si[0][i] = in4[grow + i * 128]; so[0][i] = ot4[grow + i * 128]; }
    #pragma unroll
    for (int tq = 0; tq < 4; ++tq) { qf[0][tq] = qhg[qb0 + tq * 16]; qf[0][4 + tq] = qlg[qb0 + tq * 16]; }

    #pragma unroll
    for (int kc = 0; kc < 16; ++kc) {
        const int cur = kc & 1, nxt = cur ^ 1;
        // issue next chunk's loads (stay in flight; consumed via counted waits)
        if (kc < 15) {
            const int go = grow + (kc + 1) * 8;
            #pragma unroll
            for (int i = 0; i < 4; ++i) { si[nxt][i] = in4[go + i * 128]; so[nxt][i] = ot4[go + i * 128]; }
            const int qb = qb0 + (kc + 1) * 256;
            #pragma unroll
            for (int tq = 0; tq < 4; ++tq) { qf[nxt][tq] = qhg[qb + tq * 16]; qf[nxt][4 + tq] = qlg[qb + tq * 16]; }
        }
        // CONV to wave-private LDS + register-space partial f-sums
        float4 sin_ = make_float4(0, 0, 0, 0), sot_ = make_float4(0, 0, 0, 0);
        #pragma unroll
        for (int i = 0; i < 4; ++i) {
            float4 a = si[cur][i];
            uint2 H, L; split4(a, H, L);
            const int rl = mm * 16 + lg * 4 + i;
            const int off = rl * 40 + (((c >> 1) ^ ((rl & 1) << 1)) << 3) + ((c & 1) << 2);
            *(uint2*)&Mh[off] = H;
            *(uint2*)&Ml[off] = L;
            sin_.x += wj[i] * a.x; sin_.y += wj[i] * a.y;
            sin_.z += wj[i] * a.z; sin_.w += wj[i] * a.w;
            float4 o = so[cur][i];
            sot_.x += o.x; sot_.y += o.y; sot_.z += o.z; sot_.w += o.w;
        }
        // reduce over the 4 f-quads (lanes xor 16, 32); writer = lg==0
        #pragma unroll
        for (int sh = 16; sh <= 32; sh <<= 1) {
            sin_.x += __shfl_xor(sin_.x, sh, 64); sin_.y += __shfl_xor(sin_.y, sh, 64);
            sin_.z += __shfl_xor(sin_.z, sh, 64); sin_.w += __shfl_xor(sin_.w, sh, 64);
            sot_.x += __shfl_xor(sot_.x, sh, 64); sot_.y += __shfl_xor(sot_.y, sh, 64);
            sot_.z += __shfl_xor(sot_.z, sh, 64); sot_.w += __shfl_xor(sot_.w, sh, 64);
        }
        if (lg == 0) {
            ((float4*)in_mem_base)[obase + kc * 8] = sin_;
            ((float4*)out_mem_sum)[obase + kc * 8] = sot_;
        }
        // MFMA: B-frags from this wave's own LDS rows (wave-ordered DS -> no barrier)
        #pragma unroll
        for (int tm = 0; tm < 2; ++tm) {
            const int row = (2 * w + tm) * 16 + lr;
            const int off = row * 40 + ((lg ^ ((row & 1) << 1)) << 3);
            short8v bh = *(const short8v*)&Mh[off];
            short8v bl = *(const short8v*)&Ml[off];
            __builtin_amdgcn_s_setprio(1);
            #pragma unroll
            for (int tq = 0; tq < 4; ++tq) {
                short8v ah = qf[cur][tq], al = qf[cur][4 + tq];
                acc[tm][tq] = __builtin_amdgcn_mfma_f32_16x16x32_bf16(ah, bh, acc[tm][tq], 0, 0, 0);
                acc[tm][tq] = __builtin_amdgcn_mfma_f32_16x16x32_bf16(ah, bl, acc[tm][tq], 0, 0, 0);
                acc[tm][tq] = __builtin_amdgcn_mfma_f32_16x16x32_bf16(al, bh, acc[tm][tq], 0, 0, 0);
            }
            __builtin_amdgcn_s_setprio(0);
        }
    }

    // masks + max over f (16-lane groups) -> att_qm; wave w owns m-tiles 2w,2w+1
    #pragma unroll
    for (int tm = 0; tm < 2; ++tm) {
        int m = m0 + 2 * w + tm;
        float cmv = ctx_mask[((size_t)b * M_ + m) * F_ + lr];
        #pragma unroll
        for (int tq = 0; tq < 4; ++tq) {
            #pragma unroll
            for (int rg = 0; rg < 4; ++rg) {
                int q = tq * 16 + lg * 4 + rg;
                float qmv = query_mask[b * Q_ + q];
                float v = acc[tm][tq][rg];
                v = cmv * v - (1.0f - cmv) * INF_F;
                v = qmv * v - (1.0f - qmv) * INF_F;
                #pragma unroll
                for (int sh = 1; sh < 16; sh <<= 1) v = fmaxf(v, __shfl_xor(v, sh, 64));
                if (lr == 0)
                    att_qm[((size_t)b * Q_ + q) * M_ + m] = v;
            }
        }
    }
}

// K2: softmax over M (in-block) + new_query = query + probs @ out_mem_sum; 8 q/block
__global__ __launch_bounds__(128) void k_new_query(
    const float* __restrict__ att, const float* __restrict__ query,
    const float* __restrict__ out_sum, float* __restrict__ new_q)
{
    __shared__ float P[8][512];
    int bid = blockIdx.x;
    int b = bid & 15, qc = bid >> 4;
    int t = threadIdx.x;
    {
        int qi = t >> 4, l16 = t & 15;
        const float* row = att + ((size_t)b * Q_ + qc * 8 + qi) * M_;
        float vals[32]; float mx = -INF_F;
        #pragma unroll
        for (int i = 0; i < 32; ++i) { vals[i] = row[l16 + i * 16]; mx = fmaxf(mx, vals[i]); }
        #pragma unroll
        for (int s = 1; s < 16; s <<= 1) mx = fmaxf(mx, __shfl_xor(mx, s, 64));
        float sm = 0.f;
        #pragma unroll
        for (int i = 0; i < 32; ++i) { vals[i] = __expf(vals[i] - mx); sm += vals[i]; }
        #pragma unroll
        for (int s = 1; s < 16; s <<= 1) sm += __shfl_xor(sm, s, 64);
        float inv = 1.0f / sm;
        #pragma unroll
        for (int i = 0; i < 32; ++i) P[qi][l16 + i * 16] = vals[i] * inv;
    }
    __syncthreads();
    int c = t;
    const float4* o4 = (const float4*)out_sum + (size_t)b * M_ * 128 + c;
    const float4* q4 = (const float4*)query + ((size_t)b * Q_ + qc * 8) * 128 + c;
    float4 acc[8];
    #pragma unroll
    for (int qi = 0; qi < 8; ++qi) acc[qi] = q4[(size_t)qi * 128];
    for (int mm = 0; mm < M_; mm += 4) {
        float4 o0 = o4[(size_t)(mm + 0) * 128];
        float4 o1 = o4[(size_t)(mm + 1) * 128];
        float4 o2 = o4[(size_t)(mm + 2) * 128];
        float4 o3 = o4[(size_t)(mm + 3) * 128];
        #pragma unroll
        for (int qi = 0; qi < 8; ++qi) {
            float4 p = *(const float4*)&P[qi][mm];
            acc[qi].x += p.x * o0.x + p.y * o1.x + p.z * o2.x + p.w * o3.x;
            acc[qi].y += p.x * o0.y + p.y * o1.y + p.z * o2.y + p.w * o3.y;
            acc[qi].z += p.x * o0.z + p.y * o1.z + p.z * o2.z + p.w * o3.z;
            acc[qi].w += p.x * o0.w + p.y * o1.w + p.z * o2.w + p.w * o3.w;
        }
    }
    float4* n4 = (float4*)new_q + ((size_t)b * Q_ + qc * 8) * 128 + c;
    #pragma unroll
    for (int qi = 0; qi < 8; ++qi) n4[(size_t)qi * 128] = acc[qi];
}

// K3: softmax over Q (in-block) + in_mem += p2 @ new_query; 8 m/block
__global__ __launch_bounds__(128) void k_in_mem(
    const float* __restrict__ att, const float* __restrict__ new_q,
    float* __restrict__ in_mem_io)
{
    __shared__ float P[8][64];
    int bid = blockIdx.x;
    int b = bid & 15, mc = bid >> 4;
    int m0 = mc * 8;
    int t = threadIdx.x;
    {
        int mi = t >> 4, l16 = t & 15;
        float v[4]; float mx = -INF_F;
        #pragma unroll
        for (int i = 0; i < 4; ++i) {
            v[i] = att[((size_t)b * Q_ + l16 + i * 16) * M_ + m0 + mi];
            mx = fmaxf(mx, v[i]);
        }
        #pragma unroll
        for (int s = 1; s < 16; s <<= 1) mx = fmaxf(mx, __shfl_xor(mx, s, 64));
        float sm = 0.f;
        #pragma unroll
        for (int i = 0; i < 4; ++i) { v[i] = __expf(v[i] - mx); sm += v[i]; }
        #pragma unroll
        for (int s = 1; s < 16; s <<= 1) sm += __shfl_xor(sm, s, 64);
        float inv = 1.0f / sm;
        #pragma unroll
        for (int i = 0; i < 4; ++i) P[mi][l16 + i * 16] = v[i] * inv;
    }
    __syncthreads();
    int c = t;
    float4* io = (float4*)in_mem_io + ((size_t)b * M_ + m0) * 128 + c;
    const float4* n4 = (const float4*)new_q + (size_t)b * Q_ * 128 + c;
    float4 acc[8];
    #pragma unroll
    for (int mi = 0; mi < 8; ++mi) acc[mi] = io[(size_t)mi * 128];
    for (int q = 0; q < Q_; q += 4) {
        float4 n0 = n4[(size_t)(q + 0) * 128];
        float4 n1 = n4[(size_t)(q + 1) * 128];
        float4 n2 = n4[(size_t)(q + 2) * 128];
        float4 n3 = n4[(size_t)(q + 3) * 128];
        #pragma unroll
        for (int mi = 0; mi < 8; ++mi) {
            float4 p = *(const float4*)&P[mi][q];
            acc[mi].x += p.x * n0.x + p.y * n1.x + p.z * n2.x + p.w * n3.x;
            acc[mi].y += p.x * n0.y + p.y * n1.y + p.z * n2.y + p.w * n3.y;
            acc[mi].z += p.x * n0.z + p.y * n1.z + p.z * n2.z + p.w * n3.z;
            acc[mi].w += p.x * n0.w + p.y * n1.w + p.z * n2.w + p.w * n3.w;
        }
    }
    #pragma unroll
    for (int mi = 0; mi < 8; ++mi) io[(size_t)mi * 128] = acc[mi];
}

extern "C" void kernel_launch(void* const* d_in, const int* in_sizes, int n_in,
                              void* d_out, int out_size, void* d_ws, size_t ws_size,
                              hipStream_t stream)
{
    const float* query      = (const float*)d_in[0];
    const float* in_mem     = (const float*)d_in[1];
    const float* out_mem    = (const float*)d_in[2];
    const float* ctx_mask   = (const float*)d_in[3];
    const float* query_mask = (const float*)d_in[4];

    float* out = (float*)d_out;
    float* new_q      = out;                             // B*Q*D
    float* in_mem_out = out + (size_t)B_*Q_*D_;          // B*M*D
    float* out_mem_o  = in_mem_out + (size_t)B_*M_*D_;   // B*M*D

    float* ws       = (float*)d_ws;
    float* att_qm   = ws;                                // B*Q*M floats (2 MB)
    short8v* qh     = (short8v*)(ws + (size_t)B_*Q_*M_); // 65536 units (1 MB)
    short8v* ql     = qh + 65536;                        // 1 MB

    hipLaunchKernelGGL(k_q_split, dim3(256), dim3(256), 0, stream, query, qh, ql);
    hipLaunchKernelGGL(k_att_fused, dim3((M_/8) * B_), dim3(256), 0, stream,
                       qh, ql, in_mem, out_mem, ctx_mask, query_mask,
                       att_qm, in_mem_out, out_mem_o);
    hipLaunchKernelGGL(k_new_query, dim3(8 * B_), dim3(128), 0, stream,
                       att_qm, query, out_mem_o, new_q);
    hipLaunchKernelGGL(k_in_mem, dim3(64 * B_), dim3(128), 0, stream,
                       att_qm, new_q, in_mem_out);
}